// Round 16
// baseline (1393.153 us; speedup 1.0000x reference)
//
#include <hip/hip_runtime.h>
#include <hip/hip_bf16.h>
#include <cstdint>

typedef __attribute__((ext_vector_type(8))) short bf16x8;
typedef __attribute__((ext_vector_type(4))) float f32x4;
typedef __attribute__((ext_vector_type(4))) unsigned int u32x4;

#define V_ 32000
#define E_ 512
#define H_ 1024
#define B_ 32
#define S_ 128

#define L1WG 16   // 16 WGs x 64 cols (layer 1)
#define L2WG 32   // 32 WGs x 32 cols (layer 2)
#define NWGS 48
#define NTILES 250  // V_/128 n-bands
#define GWGS 208    // persistent GEMM WGs (48+208 = 256 = #CUs)

// ---- async global->LDS, 16B per lane (dest = wave-uniform base + lane*16) ----
typedef __attribute__((address_space(1))) unsigned int* gas1_t;
typedef __attribute__((address_space(3))) unsigned int* las3_t;
__device__ __forceinline__ void load_lds16(const void* g, void* l) {
  __builtin_amdgcn_global_load_lds((gas1_t)g, (las3_t)l, 16, 0, 0);
}

// ---- coherent exchange primitives (visibility proven R4..R15) ----
__device__ __forceinline__ void ldx4_sc(u32x4* d, const void* p) {
  asm volatile("global_load_dwordx4 %0, %1, off sc0 sc1" : "=v"(*d) : "v"(p) : "memory");
}
__device__ __forceinline__ unsigned ld_sc(const unsigned* p) {
  unsigned d;
  asm volatile("global_load_dword %0, %1, off sc0 sc1\n\ts_waitcnt vmcnt(0)"
               : "=v"(d) : "v"(p) : "memory");
  return d;
}
__device__ __forceinline__ void st_swap(unsigned* p, unsigned v) {
  asm volatile("global_atomic_swap %0, %1, off sc1" :: "v"(p), "v"(v) : "memory");
}
__device__ __forceinline__ void st_swap2(uint2* p, uint2 v) {
  asm volatile("global_atomic_swap_x2 %0, %1, off sc1" :: "v"(p), "v"(v) : "memory");
}
#define WAITVM0()                                     \
  asm volatile("s_waitcnt vmcnt(0)" ::: "memory");    \
  __builtin_amdgcn_sched_barrier(0)
#define WAITVM6()                                     \
  asm volatile("s_waitcnt vmcnt(6)" ::: "memory");    \
  __builtin_amdgcn_sched_barrier(0)

__device__ __forceinline__ unsigned short bfbits(float x) {
  __hip_bfloat16 b = __float2bfloat16(x);
  union { __hip_bfloat16 b; unsigned short u; } c;
  c.b = b;
  return c.u;
}

// pack 4 rows x 4 cols into one uint2 per lane (2 shfl_xor rounds) — proven R5+
__device__ __forceinline__ uint2 pack_rows(const float f[4], int lane, int j) {
  uint2 v2[4];
#pragma unroll
  for (int r = 0; r < 4; ++r) {
    const float o = __shfl_xor(f[r], 1);
    const float lo = (lane & 1) ? o : f[r];
    const float hi = (lane & 1) ? f[r] : o;
    const unsigned pk = (unsigned)bfbits(lo) | ((unsigned)bfbits(hi) << 16);
    const unsigned q2 = __shfl_xor(pk, 2);
    v2[r].x = (j & 2) ? q2 : pk;
    v2[r].y = (j & 2) ? pk : q2;
  }
  const int rs = lane & 3;
  return rs == 0 ? v2[0] : rs == 1 ? v2[1] : rs == 2 ? v2[2] : v2[3];
}

// ---- transpose + f32->bf16 : src[R][C] -> dst[C][R] (W0 only) ----
__global__ __launch_bounds__(256) void transpose_f32_bf16(
    const float* __restrict__ src, __hip_bfloat16* __restrict__ dst, int R, int C) {
  __shared__ float tile[32][33];
  const int c0 = blockIdx.x << 5, r0 = blockIdx.y << 5;
  const int tx = threadIdx.x & 31, ty = threadIdx.x >> 5;
#pragma unroll
  for (int i = 0; i < 32; i += 8)
    tile[ty + i][tx] = src[(size_t)(r0 + ty + i) * C + (c0 + tx)];
  __syncthreads();
#pragma unroll
  for (int i = 0; i < 32; i += 8)
    dst[(size_t)(c0 + ty + i) * R + (r0 + tx)] = __float2bfloat16(tile[tx][ty + i]);
}

// ---- embedding gather -> bf16, rows ordered r = t*32 + b ----
__global__ __launch_bounds__(256) void gather_embed(
    const int* __restrict__ tokens, const float* __restrict__ emb,
    __hip_bfloat16* __restrict__ Xg) {
  const int r = blockIdx.x;
  const int t = r >> 5, b = r & 31;
  const int tok = tokens[b * S_ + t];
  const float* e = emb + (size_t)tok * E_;
  __hip_bfloat16* o = Xg + (size_t)r * E_;
  for (int k = threadIdx.x; k < E_; k += 256) o[k] = __float2bfloat16(e[k]);
}

// ---- f32 weight [K][ncols] -> MFMA B-fragment-linear bf16 ----
__global__ __launch_bounds__(256) void make_frag_w(
    const float* __restrict__ W, __hip_bfloat16* __restrict__ F, int ncols) {
  const int idx = blockIdx.x * 256 + threadIdx.x;
  const int lane = idx & 63, kb = (idx >> 6) & 31, g = idx >> 11;
  const int j = (g << 4) + (lane & 15);
  const int kbase = (kb << 5) + ((lane >> 4) << 3);
  __hip_bfloat16* o = F + (size_t)idx * 8;
#pragma unroll
  for (int e = 0; e < 8; ++e) o[e] = __float2bfloat16(W[(size_t)(kbase + e) * ncols + j]);
}

// ---- standalone 128x128 GEMM (xw only): 2-phase dbuf + XCD swizzle ----
__global__ __launch_bounds__(256) void gemm_bf16_tn(
    const __hip_bfloat16* __restrict__ A, const __hip_bfloat16* __restrict__ Bt,
    const float* __restrict__ bias, float* __restrict__ C, int M, int N, int K) {
  __shared__ __hip_bfloat16 ldsA[2][128 * 64];
  __shared__ __hip_bfloat16 ldsB[2][128 * 64];
  const int nwg = gridDim.x * gridDim.y;
  int L = blockIdx.y * gridDim.x + blockIdx.x;
  L = ((L & 7) * (nwg >> 3)) + (L >> 3);
  const int m0 = (L / gridDim.x) << 7;
  const int n0 = (L % gridDim.x) << 7;
  const int tid = threadIdx.x, wave = tid >> 6, lane = tid & 63;
  const int wr = wave >> 1, wc = wave & 1;
  f32x4 acc[4][4];
#pragma unroll
  for (int i = 0; i < 4; ++i)
#pragma unroll
    for (int jj = 0; jj < 4; ++jj) acc[i][jj] = (f32x4){0.f, 0.f, 0.f, 0.f};

  auto stage = [&](int buf, int k0) {
#pragma unroll
    for (int i = 0; i < 4; ++i) {
      const int c = i * 4 + wave;
      const int idx = (c << 6) + lane;
      const int row = idx >> 3, kk = (idx & 7) << 3;
      load_lds16(A + (size_t)(m0 + row) * K + (k0 + kk), &ldsA[buf][c * 512]);
      load_lds16(Bt + (size_t)(n0 + row) * K + (k0 + kk), &ldsB[buf][c * 512]);
    }
  };
  stage(0, 0);
  __syncthreads();
  int cur = 0;
  for (int k0 = 0; k0 < K; k0 += 64) {
    if (k0 + 64 < K) stage(cur ^ 1, k0 + 64);
    __builtin_amdgcn_s_setprio(1);
#pragma unroll
    for (int ks = 0; ks < 2; ++ks) {
      bf16x8 af[4], bfr[4];
#pragma unroll
      for (int mi = 0; mi < 4; ++mi)
        af[mi] = *(const bf16x8*)(&ldsA[cur][0] +
                                  (((wr << 6) + (mi << 4) + (lane & 15)) << 6) +
                                  (ks << 5) + ((lane >> 4) << 3));
#pragma unroll
      for (int ni = 0; ni < 4; ++ni)
        bfr[ni] = *(const bf16x8*)(&ldsB[cur][0] +
                                   (((wc << 6) + (ni << 4) + (lane & 15)) << 6) +
                                   (ks << 5) + ((lane >> 4) << 3));
#pragma unroll
      for (int mi = 0; mi < 4; ++mi)
#pragma unroll
        for (int ni = 0; ni < 4; ++ni)
          acc[mi][ni] =
              __builtin_amdgcn_mfma_f32_16x16x32_bf16(af[mi], bfr[ni], acc[mi][ni], 0, 0, 0);
    }
    __builtin_amdgcn_s_setprio(0);
    __syncthreads();
    cur ^= 1;
  }
#pragma unroll
  for (int mi = 0; mi < 4; ++mi) {
#pragma unroll
    for (int ni = 0; ni < 4; ++ni) {
      const int n = n0 + (wc << 6) + (ni << 4) + (lane & 15);
      const float bn = bias[n];
#pragma unroll
      for (int r = 0; r < 4; ++r) {
        const int m = m0 + (wr << 6) + (mi << 4) + ((lane >> 4) << 2) + r;
        C[(size_t)m * N + n] = acc[mi][ni][r] + bn;
      }
    }
  }
}

// ============================================================================
// FUSED kernel. blockIdx 0..47: R9 recurrence (Yf published frag-linear).
// blockIdx 48..255: PERSISTENT GEMM WGs — each owns n-band(s) nt = wg, wg+208
// and loops mt=0..15 in flag order (consume-as-produced). Per-tile K-loop:
// 2-deep dbuf with COUNTED vmcnt(6) + raw s_barrier (never drain mid-loop).
// All layouts/addresses identical to R15 (passed); only scheduling changed.
// ============================================================================
__global__ __launch_bounds__(512, 1) void rnn_vocab_fused(
    const __hip_bfloat16* __restrict__ U0f, const __hip_bfloat16* __restrict__ W1f,
    const __hip_bfloat16* __restrict__ U1f, const float* __restrict__ xw,
    const float* __restrict__ b1,
    __hip_bfloat16* __restrict__ h0buf,  // [4][32][1024] ring-4
    __hip_bfloat16* __restrict__ h1buf,  // [2][32][1024] ring-2
    __hip_bfloat16* __restrict__ Yf,     // frag-linear A: 8MB
    unsigned* __restrict__ flags,        // [48*16] dwords, zeroed
    const __hip_bfloat16* __restrict__ Wdf,  // frag-linear Wd: 64MB
    const float* __restrict__ bd, float* __restrict__ out) {
  __shared__ char smem[135168];
  const int tid = threadIdx.x, wave = tid >> 6, lane = tid & 63;

  if (blockIdx.x < NWGS) {
    // ======================= recurrence (R9 verbatim) =======================
    char* sA0 = smem;
    char* sA1 = smem + 65536;
    float* pad = (float*)(smem + 131072);
    const int g = blockIdx.x;
    const bool isL1 = (g < L1WG);
    const int mi = wave & 1;
    const int cg = isL1 ? (wave >> 1) : ((wave >> 1) & 1);
    const int mat = isL1 ? 0 : (wave >> 2);
    const int colbase = isL1 ? (g << 6) : ((g - L1WG) << 5);
    const int j = colbase + (cg << 4) + (lane & 15);
    const int gg = (colbase >> 4) + cg;
    const int rowbase = (mi << 4) + ((lane >> 4) << 2);
    const int rs = lane & 3;
    const int ra = (mi << 4) + (lane & 15);
    const int q4 = (lane >> 4) << 4;
    const float b1j = b1[j];

    const __hip_bfloat16* wb = isL1 ? U0f : (mat == 0 ? W1f : U1f);
    bf16x8 wfr[32];
#pragma unroll
    for (int kb = 0; kb < 32; ++kb)
      wfr[kb] = *(const bf16x8*)(wb + (size_t)((((gg << 5) + kb) << 6) + lane) * 8);

    if (!isL1) {
      for (int i = tid; i < 4096; i += 512) *(uint4*)(sA1 + i * 16) = (uint4){0u, 0u, 0u, 0u};
    }
    __syncthreads();

    const int stg_row = tid >> 7;
    const int stg_colb = (tid & 127) << 4;
    const unsigned* fpoll = flags + ((lane < NWGS ? lane : NWGS - 1) << 4);

    if (isL1) {
      for (int p = 0; p < S_; ++p) {
        const float* xrow = xw + ((size_t)p << 15);
        float xv[4];
#pragma unroll
        for (int r = 0; r < 4; ++r) xv[r] = xrow[(rowbase + r) * H_ + j];
        if (p >= 1) {
          const unsigned tgt =
              (lane < L1WG) ? (unsigned)p : (p >= 3 ? (unsigned)(p - 3) : 0u);
          unsigned v;
          do { v = ld_sc(fpoll); } while (__any(v < tgt));
          const char* src0 = (const char*)(h0buf + ((size_t)((p - 1) & 3) << 15));
          u32x4 t0[8];
#pragma unroll
          for (int i = 0; i < 8; ++i) ldx4_sc(&t0[i], src0 + (size_t)(((i << 9) + tid) << 4));
          WAITVM0();
#pragma unroll
          for (int i = 0; i < 8; ++i) {
            const int row = stg_row + (i << 2);
            *(u32x4*)(sA0 + (row << 11) + (stg_colb ^ ((row & 7) << 4))) = t0[i];
          }
          __syncthreads();
        }
        f32x4 acc = {0.f, 0.f, 0.f, 0.f};
        if (p >= 1) {
#pragma unroll
          for (int kb = 0; kb < 32; ++kb) {
            bf16x8 a = *(const bf16x8*)(
                sA0 + (ra << 11) + ((((kb << 6) + q4)) ^ ((ra & 7) << 4)));
            acc = __builtin_amdgcn_mfma_f32_16x16x32_bf16(a, wfr[kb], acc, 0, 0, 0);
          }
        }
        float f[4];
#pragma unroll
        for (int r = 0; r < 4; ++r) f[r] = tanhf(acc[r] + xv[r]);
        uint2 vsel = pack_rows(f, lane, j);
        uint2* h4 = (uint2*)(h0buf + ((size_t)(p & 3) << 15));
        st_swap2(h4 + (rowbase + rs) * (H_ / 4) + (j >> 2), vsel);
        WAITVM0();
        __syncthreads();
        if (tid == 0) st_swap(flags + (g << 4), (unsigned)(p + 1));
      }
    } else {
      for (int t = 0; t < S_; ++t) {
        {
          const unsigned tgt = (lane < L1WG) ? (unsigned)(t + 1) : (unsigned)t;
          unsigned v;
          do { v = ld_sc(fpoll); } while (__any(v < tgt));
        }
        {
          const char* src0 = (const char*)(h0buf + ((size_t)(t & 3) << 15));
          u32x4 t0[8], t1[8];
#pragma unroll
          for (int i = 0; i < 8; ++i) ldx4_sc(&t0[i], src0 + (size_t)(((i << 9) + tid) << 4));
          if (t >= 1) {
            const char* src1 = (const char*)(h1buf + ((size_t)((t - 1) & 1) << 15));
#pragma unroll
            for (int i = 0; i < 8; ++i) ldx4_sc(&t1[i], src1 + (size_t)(((i << 9) + tid) << 4));
          }
          WAITVM0();
#pragma unroll
          for (int i = 0; i < 8; ++i) {
            const int row = stg_row + (i << 2);
            *(u32x4*)(sA0 + (row << 11) + (stg_colb ^ ((row & 7) << 4))) = t0[i];
          }
          if (t >= 1) {
#pragma unroll
            for (int i = 0; i < 8; ++i) {
              const int row = stg_row + (i << 2);
              *(u32x4*)(sA1 + (row << 11) + (stg_colb ^ ((row & 7) << 4))) = t1[i];
            }
          }
          __syncthreads();
        }
        const char* sA = (mat == 0) ? sA0 : sA1;
        f32x4 acc = {0.f, 0.f, 0.f, 0.f};
#pragma unroll
        for (int kb = 0; kb < 32; ++kb) {
          bf16x8 a = *(const bf16x8*)(
              sA + (ra << 11) + ((((kb << 6) + q4)) ^ ((ra & 7) << 4)));
          acc = __builtin_amdgcn_mfma_f32_16x16x32_bf16(a, wfr[kb], acc, 0, 0, 0);
        }
        const int pair = wave & 3;
        if (mat == 0) *(f32x4*)(pad + pair * 256 + lane * 4) = acc;
        __syncthreads();
        if (mat == 1) {
          f32x4 accW = *(const f32x4*)(pad + pair * 256 + lane * 4);
          float f[4];
#pragma unroll
          for (int r = 0; r < 4; ++r) f[r] = tanhf(acc[r] + accW[r] + b1j);
          uint2 vsel = pack_rows(f, lane, j);
          const int bb = rowbase + rs;
          uint2* h4 = (uint2*)(h1buf + ((size_t)(t & 1) << 15));
          st_swap2(h4 + bb * (H_ / 4) + (j >> 2), vsel);
          // Yf publish in frag-linear A layout (R15-verified)
          const int jb = j & ~3;
          const size_t fo =
              (((size_t)((t << 1) + (bb >> 4)) << 5) + (jb >> 5)) * 64 +
              (((jb >> 3) & 3) << 4) + (bb & 15);
          st_swap2((uint2*)((char*)Yf + fo * 16 + ((jb & 7) << 1)), vsel);
        }
        WAITVM0();
        __syncthreads();
        if (tid == 0) st_swap(flags + (g << 4), (unsigned)(t + 1));
      }
    }
    return;
  }

  // ================== persistent vocab GEMM WGs (208) ==================
  const int wg = blockIdx.x - NWGS;
  const int wr = wave >> 1, wc = wave & 1;  // 4M x 2N waves, 64x64 each
  const char* Yc = (const char*)Yf;
  const char* Wc = (const char*)Wdf;

  for (int nt = wg; nt < NTILES; nt += GWGS) {
    const int n0 = nt << 7;
    for (int mt = 0; mt < 16; ++mt) {
      const int m0 = mt << 8;
      // poll: this m-tile's 8 steps published (L2 flags >= 8*mt+8)
      {
        const unsigned tgt = (unsigned)((mt << 3) + 8);
        if (wave == 0) {
          const unsigned* fp = flags + ((L1WG + (lane & 31)) << 4);
          while (true) {
            unsigned v = ld_sc(fp);
            if (!__any(v < tgt)) break;
            asm volatile("s_sleep 4");
          }
        }
        __syncthreads();  // also drains previous tile's stores/loads
      }
      f32x4 acc[4][4];
#pragma unroll
      for (int i = 0; i < 4; ++i)
#pragma unroll
        for (int jj = 0; jj < 4; ++jj) acc[i][jj] = (f32x4){0.f, 0.f, 0.f, 0.f};

      auto stageA = [&](int buf, int k0) {  // 32 chunks, 4/wave
#pragma unroll
        for (int i = 0; i < 4; ++i) {
          const int c = (i << 3) + wave;
          const char* src = Yc +
              ((((size_t)(m0 >> 4) + (c >> 1)) << 5) + (k0 >> 5) + (c & 1)) * 1024 +
              (lane << 4);
          load_lds16(src, smem + buf * 32768 + c * 1024);
        }
      };
      auto stageB = [&](int buf, int k0) {  // 16 chunks, 2/wave
#pragma unroll
        for (int i = 0; i < 2; ++i) {
          const int c = (i << 3) + wave;
          const char* src = Wc +
              ((((size_t)(n0 >> 4) + (c >> 1)) << 5) + (k0 >> 5) + (c & 1)) * 1024 +
              (lane << 4);
          load_lds16(src, smem + 65536 + buf * 16384 + c * 1024);
        }
      };

      stageA(0, 0);
      stageB(0, 0);
      stageA(1, 64);
      stageB(1, 64);
      WAITVM6();  // tile0's 6 (per wave) done; tile1's 6 in flight
      __builtin_amdgcn_sched_barrier(0);
      __builtin_amdgcn_s_barrier();
      int cur = 0;
      for (int k0 = 0; k0 < H_; k0 += 64) {
        __builtin_amdgcn_s_setprio(1);
#pragma unroll
        for (int ks = 0; ks < 2; ++ks) {
          bf16x8 af[4], bfr[4];
#pragma unroll
          for (int mi = 0; mi < 4; ++mi)
            af[mi] = *(const bf16x8*)(smem + cur * 32768 +
                                      ((((wr << 2) + mi) << 1) + ks) * 1024 + (lane << 4));
#pragma unroll
          for (int ni = 0; ni < 4; ++ni)
            bfr[ni] = *(const bf16x8*)(smem + 65536 + cur * 16384 +
                                       ((((wc << 2) + ni) << 1) + ks) * 1024 + (lane << 4));
#pragma unroll
          for (int mi = 0; mi < 4; ++mi)
#pragma unroll
            for (int ni = 0; ni < 4; ++ni)
              acc[mi][ni] = __builtin_amdgcn_mfma_f32_16x16x32_bf16(af[mi], bfr[ni],
                                                                    acc[mi][ni], 0, 0, 0);
        }
        __builtin_amdgcn_s_setprio(0);
        if (k0 + 64 < H_) {
          __builtin_amdgcn_sched_barrier(0);
          __builtin_amdgcn_s_barrier();  // all waves done reading buf[cur]
          if (k0 + 128 < H_) {
            stageA(cur, k0 + 128);       // refill freed buffer
            stageB(cur, k0 + 128);
            WAITVM6();                   // prev tile's 6 done; new 6 in flight
          } else {
            WAITVM0();                   // last tile: drain
          }
          __builtin_amdgcn_sched_barrier(0);
          __builtin_amdgcn_s_barrier();  // buf[cur^1] certified staged
          cur ^= 1;
        }
      }
      // epilogue: m = t*32+b -> out row = b*128+t ; add bd
#pragma unroll
      for (int mi = 0; mi < 4; ++mi) {
#pragma unroll
        for (int ni = 0; ni < 4; ++ni) {
          const int n = n0 + (wc << 6) + (ni << 4) + (lane & 15);
          const float bn = bd[n];
#pragma unroll
          for (int r = 0; r < 4; ++r) {
            const int m = m0 + (wr << 6) + (mi << 4) + ((lane >> 4) << 2) + r;
            const size_t orow = (size_t)(m & 31) * S_ + (m >> 5);
            out[orow * V_ + n] = acc[mi][ni][r] + bn;
          }
        }
      }
    }
  }
}

extern "C" void kernel_launch(void* const* d_in, const int* in_sizes, int n_in, void* d_out,
                              int out_size, void* d_ws, size_t ws_size, hipStream_t stream) {
  const int* tokens = (const int*)d_in[0];
  const float* emb = (const float*)d_in[1];
  const float* W0 = (const float*)d_in[2];
  const float* U0 = (const float*)d_in[3];
  const float* b0 = (const float*)d_in[4];
  const float* W1 = (const float*)d_in[5];
  const float* U1 = (const float*)d_in[6];
  const float* b1 = (const float*)d_in[7];
  const float* Wd = (const float*)d_in[8];
  const float* bd = (const float*)d_in[9];
  float* out = (float*)d_out;

  char* ws = (char*)d_ws;
  __hip_bfloat16* Wdf = (__hip_bfloat16*)ws;  ws += (size_t)V_ * H_ * 2;       // 64MB frag-linear
  __hip_bfloat16* W0t = (__hip_bfloat16*)ws;  ws += (size_t)H_ * E_ * 2;       // 1MB
  __hip_bfloat16* Xg = (__hip_bfloat16*)ws;   ws += (size_t)4096 * E_ * 2;     // 4MB
  __hip_bfloat16* U0f = (__hip_bfloat16*)ws;  ws += (size_t)H_ * H_ * 2;       // 2MB
  __hip_bfloat16* W1f = (__hip_bfloat16*)ws;  ws += (size_t)H_ * H_ * 2;       // 2MB
  __hip_bfloat16* U1f = (__hip_bfloat16*)ws;  ws += (size_t)H_ * H_ * 2;       // 2MB
  float* xw = (float*)ws;                     ws += (size_t)4096 * H_ * 4;     // 16MB
  __hip_bfloat16* h0buf = (__hip_bfloat16*)ws; ws += 4 * B_ * H_ * 2;          // 256KB
  __hip_bfloat16* h1buf = (__hip_bfloat16*)ws; ws += 2 * B_ * H_ * 2;          // 128KB
  __hip_bfloat16* Yf = (__hip_bfloat16*)ws;   ws += (size_t)4096 * H_ * 2;     // 8MB frag-linear
  unsigned* flags = (unsigned*)ws;            ws += 4096;

  // prep
  transpose_f32_bf16<<<dim3(H_ / 32, E_ / 32), 256, 0, stream>>>(W0, W0t, E_, H_);
  gather_embed<<<4096, 256, 0, stream>>>(tokens, emb, Xg);
  make_frag_w<<<512, 256, 0, stream>>>(U0, U0f, H_);
  make_frag_w<<<512, 256, 0, stream>>>(W1, W1f, H_);
  make_frag_w<<<512, 256, 0, stream>>>(U1, U1f, H_);
  make_frag_w<<<16000, 256, 0, stream>>>(Wd, Wdf, V_);  // frag-linear Wd
  hipMemsetAsync(flags, 0, 4096, stream);

  // xw = Xg @ W0 + b0   (M=4096, N=1024, K=512)
  gemm_bf16_tn<<<dim3(H_ / 128, 4096 / 128), 256, 0, stream>>>(Xg, W0t, b0, xw, 4096, H_, E_);

  // fused: recurrence (48 WGs) + persistent vocab GEMM (208 WGs) = 256 WGs
  rnn_vocab_fused<<<NWGS + GWGS, 512, 0, stream>>>(U0f, W1f, U1f, xw, b1, h0buf, h1buf, Yf,
                                                   flags, Wdf, bd, out);
}

// Round 17
// 1088.288 us; speedup vs baseline: 1.2801x; 1.2801x over previous
//
#include <hip/hip_runtime.h>
#include <hip/hip_bf16.h>
#include <cstdint>

typedef __attribute__((ext_vector_type(8))) short bf16x8;
typedef __attribute__((ext_vector_type(4))) float f32x4;
typedef __attribute__((ext_vector_type(4))) unsigned int u32x4;

#define V_ 32000
#define E_ 512
#define H_ 1024
#define B_ 32
#define S_ 128

#define L1WG 16   // 16 WGs x 64 cols (layer 1)
#define L2WG 32   // 32 WGs x 32 cols (layer 2)
#define NWGS 48
#define NTILES 250          // V_/128 n-bands
#define GWGS (16 * NTILES)  // one-tile GEMM WGs, mt-major dispatch

// ---- async global->LDS, 16B per lane (dest = wave-uniform base + lane*16) ----
typedef __attribute__((address_space(1))) unsigned int* gas1_t;
typedef __attribute__((address_space(3))) unsigned int* las3_t;
__device__ __forceinline__ void load_lds16(const void* g, void* l) {
  __builtin_amdgcn_global_load_lds((gas1_t)g, (las3_t)l, 16, 0, 0);
}

// ---- coherent exchange primitives (visibility proven R4..R16) ----
__device__ __forceinline__ void ldx4_sc(u32x4* d, const void* p) {
  asm volatile("global_load_dwordx4 %0, %1, off sc0 sc1" : "=v"(*d) : "v"(p) : "memory");
}
__device__ __forceinline__ unsigned ld_sc(const unsigned* p) {
  unsigned d;
  asm volatile("global_load_dword %0, %1, off sc0 sc1\n\ts_waitcnt vmcnt(0)"
               : "=v"(d) : "v"(p) : "memory");
  return d;
}
__device__ __forceinline__ void st_swap(unsigned* p, unsigned v) {
  asm volatile("global_atomic_swap %0, %1, off sc1" :: "v"(p), "v"(v) : "memory");
}
__device__ __forceinline__ void st_swap2(uint2* p, uint2 v) {
  asm volatile("global_atomic_swap_x2 %0, %1, off sc1" :: "v"(p), "v"(v) : "memory");
}
#define WAITVM0()                                     \
  asm volatile("s_waitcnt vmcnt(0)" ::: "memory");    \
  __builtin_amdgcn_sched_barrier(0)
#define WAITVM6()                                     \
  asm volatile("s_waitcnt vmcnt(6)" ::: "memory");    \
  __builtin_amdgcn_sched_barrier(0)

__device__ __forceinline__ unsigned short bfbits(float x) {
  __hip_bfloat16 b = __float2bfloat16(x);
  union { __hip_bfloat16 b; unsigned short u; } c;
  c.b = b;
  return c.u;
}

// pack 4 rows x 4 cols into one uint2 per lane (2 shfl_xor rounds) — proven R5+
__device__ __forceinline__ uint2 pack_rows(const float f[4], int lane, int j) {
  uint2 v2[4];
#pragma unroll
  for (int r = 0; r < 4; ++r) {
    const float o = __shfl_xor(f[r], 1);
    const float lo = (lane & 1) ? o : f[r];
    const float hi = (lane & 1) ? f[r] : o;
    const unsigned pk = (unsigned)bfbits(lo) | ((unsigned)bfbits(hi) << 16);
    const unsigned q2 = __shfl_xor(pk, 2);
    v2[r].x = (j & 2) ? q2 : pk;
    v2[r].y = (j & 2) ? pk : q2;
  }
  const int rs = lane & 3;
  return rs == 0 ? v2[0] : rs == 1 ? v2[1] : rs == 2 ? v2[2] : v2[3];
}

// ---- transpose + f32->bf16 : src[R][C] -> dst[C][R] (W0 only) ----
__global__ __launch_bounds__(256) void transpose_f32_bf16(
    const float* __restrict__ src, __hip_bfloat16* __restrict__ dst, int R, int C) {
  __shared__ float tile[32][33];
  const int c0 = blockIdx.x << 5, r0 = blockIdx.y << 5;
  const int tx = threadIdx.x & 31, ty = threadIdx.x >> 5;
#pragma unroll
  for (int i = 0; i < 32; i += 8)
    tile[ty + i][tx] = src[(size_t)(r0 + ty + i) * C + (c0 + tx)];
  __syncthreads();
#pragma unroll
  for (int i = 0; i < 32; i += 8)
    dst[(size_t)(c0 + ty + i) * R + (r0 + tx)] = __float2bfloat16(tile[tx][ty + i]);
}

// ---- embedding gather -> bf16, rows ordered r = t*32 + b ----
__global__ __launch_bounds__(256) void gather_embed(
    const int* __restrict__ tokens, const float* __restrict__ emb,
    __hip_bfloat16* __restrict__ Xg) {
  const int r = blockIdx.x;
  const int t = r >> 5, b = r & 31;
  const int tok = tokens[b * S_ + t];
  const float* e = emb + (size_t)tok * E_;
  __hip_bfloat16* o = Xg + (size_t)r * E_;
  for (int k = threadIdx.x; k < E_; k += 256) o[k] = __float2bfloat16(e[k]);
}

// ---- f32 weight [K][ncols] -> MFMA B-fragment-linear bf16 ----
__global__ __launch_bounds__(256) void make_frag_w(
    const float* __restrict__ W, __hip_bfloat16* __restrict__ F, int ncols) {
  const int idx = blockIdx.x * 256 + threadIdx.x;
  const int lane = idx & 63, kb = (idx >> 6) & 31, g = idx >> 11;
  const int j = (g << 4) + (lane & 15);
  const int kbase = (kb << 5) + ((lane >> 4) << 3);
  __hip_bfloat16* o = F + (size_t)idx * 8;
#pragma unroll
  for (int e = 0; e < 8; ++e) o[e] = __float2bfloat16(W[(size_t)(kbase + e) * ncols + j]);
}

// ---- standalone 128x128 GEMM (xw only): 2-phase dbuf + XCD swizzle ----
__global__ __launch_bounds__(256) void gemm_bf16_tn(
    const __hip_bfloat16* __restrict__ A, const __hip_bfloat16* __restrict__ Bt,
    const float* __restrict__ bias, float* __restrict__ C, int M, int N, int K) {
  __shared__ __hip_bfloat16 ldsA[2][128 * 64];
  __shared__ __hip_bfloat16 ldsB[2][128 * 64];
  const int nwg = gridDim.x * gridDim.y;
  int L = blockIdx.y * gridDim.x + blockIdx.x;
  L = ((L & 7) * (nwg >> 3)) + (L >> 3);
  const int m0 = (L / gridDim.x) << 7;
  const int n0 = (L % gridDim.x) << 7;
  const int tid = threadIdx.x, wave = tid >> 6, lane = tid & 63;
  const int wr = wave >> 1, wc = wave & 1;
  f32x4 acc[4][4];
#pragma unroll
  for (int i = 0; i < 4; ++i)
#pragma unroll
    for (int jj = 0; jj < 4; ++jj) acc[i][jj] = (f32x4){0.f, 0.f, 0.f, 0.f};

  auto stage = [&](int buf, int k0) {
#pragma unroll
    for (int i = 0; i < 4; ++i) {
      const int c = i * 4 + wave;
      const int idx = (c << 6) + lane;
      const int row = idx >> 3, kk = (idx & 7) << 3;
      load_lds16(A + (size_t)(m0 + row) * K + (k0 + kk), &ldsA[buf][c * 512]);
      load_lds16(Bt + (size_t)(n0 + row) * K + (k0 + kk), &ldsB[buf][c * 512]);
    }
  };
  stage(0, 0);
  __syncthreads();
  int cur = 0;
  for (int k0 = 0; k0 < K; k0 += 64) {
    if (k0 + 64 < K) stage(cur ^ 1, k0 + 64);
    __builtin_amdgcn_s_setprio(1);
#pragma unroll
    for (int ks = 0; ks < 2; ++ks) {
      bf16x8 af[4], bfr[4];
#pragma unroll
      for (int mi = 0; mi < 4; ++mi)
        af[mi] = *(const bf16x8*)(&ldsA[cur][0] +
                                  (((wr << 6) + (mi << 4) + (lane & 15)) << 6) +
                                  (ks << 5) + ((lane >> 4) << 3));
#pragma unroll
      for (int ni = 0; ni < 4; ++ni)
        bfr[ni] = *(const bf16x8*)(&ldsB[cur][0] +
                                   (((wc << 6) + (ni << 4) + (lane & 15)) << 6) +
                                   (ks << 5) + ((lane >> 4) << 3));
#pragma unroll
      for (int mi = 0; mi < 4; ++mi)
#pragma unroll
        for (int ni = 0; ni < 4; ++ni)
          acc[mi][ni] =
              __builtin_amdgcn_mfma_f32_16x16x32_bf16(af[mi], bfr[ni], acc[mi][ni], 0, 0, 0);
    }
    __builtin_amdgcn_s_setprio(0);
    __syncthreads();
    cur ^= 1;
  }
#pragma unroll
  for (int mi = 0; mi < 4; ++mi) {
#pragma unroll
    for (int ni = 0; ni < 4; ++ni) {
      const int n = n0 + (wc << 6) + (ni << 4) + (lane & 15);
      const float bn = bias[n];
#pragma unroll
      for (int r = 0; r < 4; ++r) {
        const int m = m0 + (wr << 6) + (mi << 4) + ((lane >> 4) << 2) + r;
        C[(size_t)m * N + n] = acc[mi][ni][r] + bn;
      }
    }
  }
}

// ============================================================================
// FUSED kernel. blockIdx 0..47: R9 recurrence (Yf published frag-linear).
// blockIdx 48..: ONE-TILE GEMM WGs, mt-major dispatch (R15 scheduling — work
// conserving, no imbalance) with R16's counted-vmcnt 2-deep K-loop
// (stage flight never drained mid-loop; raw s_barrier).
// ============================================================================
__global__ __launch_bounds__(512, 1) void rnn_vocab_fused(
    const __hip_bfloat16* __restrict__ U0f, const __hip_bfloat16* __restrict__ W1f,
    const __hip_bfloat16* __restrict__ U1f, const float* __restrict__ xw,
    const float* __restrict__ b1,
    __hip_bfloat16* __restrict__ h0buf,  // [4][32][1024] ring-4
    __hip_bfloat16* __restrict__ h1buf,  // [2][32][1024] ring-2
    __hip_bfloat16* __restrict__ Yf,     // frag-linear A: 8MB
    unsigned* __restrict__ flags,        // [48*16] dwords, zeroed
    const __hip_bfloat16* __restrict__ Wdf,  // frag-linear Wd: 64MB
    const float* __restrict__ bd, float* __restrict__ out) {
  __shared__ char smem[135168];
  const int tid = threadIdx.x, wave = tid >> 6, lane = tid & 63;

  if (blockIdx.x < NWGS) {
    // ======================= recurrence (R9 verbatim) =======================
    char* sA0 = smem;
    char* sA1 = smem + 65536;
    float* pad = (float*)(smem + 131072);
    const int g = blockIdx.x;
    const bool isL1 = (g < L1WG);
    const int mi = wave & 1;
    const int cg = isL1 ? (wave >> 1) : ((wave >> 1) & 1);
    const int mat = isL1 ? 0 : (wave >> 2);
    const int colbase = isL1 ? (g << 6) : ((g - L1WG) << 5);
    const int j = colbase + (cg << 4) + (lane & 15);
    const int gg = (colbase >> 4) + cg;
    const int rowbase = (mi << 4) + ((lane >> 4) << 2);
    const int rs = lane & 3;
    const int ra = (mi << 4) + (lane & 15);
    const int q4 = (lane >> 4) << 4;
    const float b1j = b1[j];

    const __hip_bfloat16* wb = isL1 ? U0f : (mat == 0 ? W1f : U1f);
    bf16x8 wfr[32];
#pragma unroll
    for (int kb = 0; kb < 32; ++kb)
      wfr[kb] = *(const bf16x8*)(wb + (size_t)((((gg << 5) + kb) << 6) + lane) * 8);

    if (!isL1) {
      for (int i = tid; i < 4096; i += 512) *(uint4*)(sA1 + i * 16) = (uint4){0u, 0u, 0u, 0u};
    }
    __syncthreads();

    const int stg_row = tid >> 7;
    const int stg_colb = (tid & 127) << 4;
    const unsigned* fpoll = flags + ((lane < NWGS ? lane : NWGS - 1) << 4);

    if (isL1) {
      for (int p = 0; p < S_; ++p) {
        const float* xrow = xw + ((size_t)p << 15);
        float xv[4];
#pragma unroll
        for (int r = 0; r < 4; ++r) xv[r] = xrow[(rowbase + r) * H_ + j];
        if (p >= 1) {
          const unsigned tgt =
              (lane < L1WG) ? (unsigned)p : (p >= 3 ? (unsigned)(p - 3) : 0u);
          unsigned v;
          do { v = ld_sc(fpoll); } while (__any(v < tgt));
          const char* src0 = (const char*)(h0buf + ((size_t)((p - 1) & 3) << 15));
          u32x4 t0[8];
#pragma unroll
          for (int i = 0; i < 8; ++i) ldx4_sc(&t0[i], src0 + (size_t)(((i << 9) + tid) << 4));
          WAITVM0();
#pragma unroll
          for (int i = 0; i < 8; ++i) {
            const int row = stg_row + (i << 2);
            *(u32x4*)(sA0 + (row << 11) + (stg_colb ^ ((row & 7) << 4))) = t0[i];
          }
          __syncthreads();
        }
        f32x4 acc = {0.f, 0.f, 0.f, 0.f};
        if (p >= 1) {
#pragma unroll
          for (int kb = 0; kb < 32; ++kb) {
            bf16x8 a = *(const bf16x8*)(
                sA0 + (ra << 11) + ((((kb << 6) + q4)) ^ ((ra & 7) << 4)));
            acc = __builtin_amdgcn_mfma_f32_16x16x32_bf16(a, wfr[kb], acc, 0, 0, 0);
          }
        }
        float f[4];
#pragma unroll
        for (int r = 0; r < 4; ++r) f[r] = tanhf(acc[r] + xv[r]);
        uint2 vsel = pack_rows(f, lane, j);
        uint2* h4 = (uint2*)(h0buf + ((size_t)(p & 3) << 15));
        st_swap2(h4 + (rowbase + rs) * (H_ / 4) + (j >> 2), vsel);
        WAITVM0();
        __syncthreads();
        if (tid == 0) st_swap(flags + (g << 4), (unsigned)(p + 1));
      }
    } else {
      for (int t = 0; t < S_; ++t) {
        {
          const unsigned tgt = (lane < L1WG) ? (unsigned)(t + 1) : (unsigned)t;
          unsigned v;
          do { v = ld_sc(fpoll); } while (__any(v < tgt));
        }
        {
          const char* src0 = (const char*)(h0buf + ((size_t)(t & 3) << 15));
          u32x4 t0[8], t1[8];
#pragma unroll
          for (int i = 0; i < 8; ++i) ldx4_sc(&t0[i], src0 + (size_t)(((i << 9) + tid) << 4));
          if (t >= 1) {
            const char* src1 = (const char*)(h1buf + ((size_t)((t - 1) & 1) << 15));
#pragma unroll
            for (int i = 0; i < 8; ++i) ldx4_sc(&t1[i], src1 + (size_t)(((i << 9) + tid) << 4));
          }
          WAITVM0();
#pragma unroll
          for (int i = 0; i < 8; ++i) {
            const int row = stg_row + (i << 2);
            *(u32x4*)(sA0 + (row << 11) + (stg_colb ^ ((row & 7) << 4))) = t0[i];
          }
          if (t >= 1) {
#pragma unroll
            for (int i = 0; i < 8; ++i) {
              const int row = stg_row + (i << 2);
              *(u32x4*)(sA1 + (row << 11) + (stg_colb ^ ((row & 7) << 4))) = t1[i];
            }
          }
          __syncthreads();
        }
        const char* sA = (mat == 0) ? sA0 : sA1;
        f32x4 acc = {0.f, 0.f, 0.f, 0.f};
#pragma unroll
        for (int kb = 0; kb < 32; ++kb) {
          bf16x8 a = *(const bf16x8*)(
              sA + (ra << 11) + ((((kb << 6) + q4)) ^ ((ra & 7) << 4)));
          acc = __builtin_amdgcn_mfma_f32_16x16x32_bf16(a, wfr[kb], acc, 0, 0, 0);
        }
        const int pair = wave & 3;
        if (mat == 0) *(f32x4*)(pad + pair * 256 + lane * 4) = acc;
        __syncthreads();
        if (mat == 1) {
          f32x4 accW = *(const f32x4*)(pad + pair * 256 + lane * 4);
          float f[4];
#pragma unroll
          for (int r = 0; r < 4; ++r) f[r] = tanhf(acc[r] + accW[r] + b1j);
          uint2 vsel = pack_rows(f, lane, j);
          const int bb = rowbase + rs;
          uint2* h4 = (uint2*)(h1buf + ((size_t)(t & 1) << 15));
          st_swap2(h4 + bb * (H_ / 4) + (j >> 2), vsel);
          const int jb = j & ~3;
          const size_t fo =
              (((size_t)((t << 1) + (bb >> 4)) << 5) + (jb >> 5)) * 64 +
              (((jb >> 3) & 3) << 4) + (bb & 15);
          st_swap2((uint2*)((char*)Yf + fo * 16 + ((jb & 7) << 1)), vsel);
        }
        WAITVM0();
        __syncthreads();
        if (tid == 0) st_swap(flags + (g << 4), (unsigned)(t + 1));
      }
    }
    return;
  }

  // =================== one-tile vocab GEMM WGs (mt-major) ===================
  const int bid = blockIdx.x - NWGS;
  const int mt = bid / NTILES, nt = bid - mt * NTILES;
  const int m0 = mt << 8, n0 = nt << 7;
  {
    const unsigned tgt = (unsigned)((mt << 3) + 8);
    if (wave == 0) {
      const unsigned* fp = flags + ((L1WG + (lane & 31)) << 4);
      while (true) {
        unsigned v = ld_sc(fp);
        if (!__any(v < tgt)) break;
        asm volatile("s_sleep 4");
      }
    }
    __syncthreads();
  }
  const int wr = wave >> 1, wc = wave & 1;  // 4M x 2N waves, 64x64 each
  const char* Yc = (const char*)Yf;
  const char* Wc = (const char*)Wdf;
  f32x4 acc[4][4];
#pragma unroll
  for (int i = 0; i < 4; ++i)
#pragma unroll
    for (int jj = 0; jj < 4; ++jj) acc[i][jj] = (f32x4){0.f, 0.f, 0.f, 0.f};

  auto stageA = [&](int buf, int k0) {  // 32 chunks, 4/wave
#pragma unroll
    for (int i = 0; i < 4; ++i) {
      const int c = (i << 3) + wave;
      const char* src = Yc +
          ((((size_t)(m0 >> 4) + (c >> 1)) << 5) + (k0 >> 5) + (c & 1)) * 1024 +
          (lane << 4);
      load_lds16(src, smem + buf * 32768 + c * 1024);
    }
  };
  auto stageB = [&](int buf, int k0) {  // 16 chunks, 2/wave
#pragma unroll
    for (int i = 0; i < 2; ++i) {
      const int c = (i << 3) + wave;
      const char* src = Wc +
          ((((size_t)(n0 >> 4) + (c >> 1)) << 5) + (k0 >> 5) + (c & 1)) * 1024 +
          (lane << 4);
      load_lds16(src, smem + 65536 + buf * 16384 + c * 1024);
    }
  };

  stageA(0, 0);
  stageB(0, 0);
  stageA(1, 64);
  stageB(1, 64);
  WAITVM6();  // tile0's 6/wave done; tile1's 6 in flight
  __builtin_amdgcn_sched_barrier(0);
  __builtin_amdgcn_s_barrier();
  int cur = 0;
  for (int k0 = 0; k0 < H_; k0 += 64) {
    __builtin_amdgcn_s_setprio(1);
#pragma unroll
    for (int ks = 0; ks < 2; ++ks) {
      bf16x8 af[4], bfr[4];
#pragma unroll
      for (int mi = 0; mi < 4; ++mi)
        af[mi] = *(const bf16x8*)(smem + cur * 32768 +
                                  ((((wr << 2) + mi) << 1) + ks) * 1024 + (lane << 4));
#pragma unroll
      for (int ni = 0; ni < 4; ++ni)
        bfr[ni] = *(const bf16x8*)(smem + 65536 + cur * 16384 +
                                   ((((wc << 2) + ni) << 1) + ks) * 1024 + (lane << 4));
#pragma unroll
      for (int mi = 0; mi < 4; ++mi)
#pragma unroll
        for (int ni = 0; ni < 4; ++ni)
          acc[mi][ni] = __builtin_amdgcn_mfma_f32_16x16x32_bf16(af[mi], bfr[ni],
                                                                acc[mi][ni], 0, 0, 0);
    }
    __builtin_amdgcn_s_setprio(0);
    if (k0 + 64 < H_) {
      __builtin_amdgcn_sched_barrier(0);
      __builtin_amdgcn_s_barrier();  // all waves done reading buf[cur]
      if (k0 + 128 < H_) {
        stageA(cur, k0 + 128);       // refill freed buffer
        stageB(cur, k0 + 128);
        WAITVM6();                   // prev tile's 6 done; new 6 in flight
      } else {
        WAITVM0();                   // last prefetch already issued: drain
      }
      __builtin_amdgcn_sched_barrier(0);
      __builtin_amdgcn_s_barrier();  // buf[cur^1] certified staged
      cur ^= 1;
    }
  }
  // epilogue: m = t*32+b -> out row = b*128+t ; add bd
#pragma unroll
  for (int mi = 0; mi < 4; ++mi) {
#pragma unroll
    for (int ni = 0; ni < 4; ++ni) {
      const int n = n0 + (wc << 6) + (ni << 4) + (lane & 15);
      const float bn = bd[n];
#pragma unroll
      for (int r = 0; r < 4; ++r) {
        const int m = m0 + (wr << 6) + (mi << 4) + ((lane >> 4) << 2) + r;
        const size_t orow = (size_t)(m & 31) * S_ + (m >> 5);
        out[orow * V_ + n] = acc[mi][ni][r] + bn;
      }
    }
  }
}

extern "C" void kernel_launch(void* const* d_in, const int* in_sizes, int n_in, void* d_out,
                              int out_size, void* d_ws, size_t ws_size, hipStream_t stream) {
  const int* tokens = (const int*)d_in[0];
  const float* emb = (const float*)d_in[1];
  const float* W0 = (const float*)d_in[2];
  const float* U0 = (const float*)d_in[3];
  const float* b0 = (const float*)d_in[4];
  const float* W1 = (const float*)d_in[5];
  const float* U1 = (const float*)d_in[6];
  const float* b1 = (const float*)d_in[7];
  const float* Wd = (const float*)d_in[8];
  const float* bd = (const float*)d_in[9];
  float* out = (float*)d_out;

  char* ws = (char*)d_ws;
  __hip_bfloat16* Wdf = (__hip_bfloat16*)ws;  ws += (size_t)V_ * H_ * 2;       // 64MB frag-linear
  __hip_bfloat16* W0t = (__hip_bfloat16*)ws;  ws += (size_t)H_ * E_ * 2;       // 1MB
  __hip_bfloat16* Xg = (__hip_bfloat16*)ws;   ws += (size_t)4096 * E_ * 2;     // 4MB
  __hip_bfloat16* U0f = (__hip_bfloat16*)ws;  ws += (size_t)H_ * H_ * 2;       // 2MB
  __hip_bfloat16* W1f = (__hip_bfloat16*)ws;  ws += (size_t)H_ * H_ * 2;       // 2MB
  __hip_bfloat16* U1f = (__hip_bfloat16*)ws;  ws += (size_t)H_ * H_ * 2;       // 2MB
  float* xw = (float*)ws;                     ws += (size_t)4096 * H_ * 4;     // 16MB
  __hip_bfloat16* h0buf = (__hip_bfloat16*)ws; ws += 4 * B_ * H_ * 2;          // 256KB
  __hip_bfloat16* h1buf = (__hip_bfloat16*)ws; ws += 2 * B_ * H_ * 2;          // 128KB
  __hip_bfloat16* Yf = (__hip_bfloat16*)ws;   ws += (size_t)4096 * H_ * 2;     // 8MB frag-linear
  unsigned* flags = (unsigned*)ws;            ws += 4096;

  // prep
  transpose_f32_bf16<<<dim3(H_ / 32, E_ / 32), 256, 0, stream>>>(W0, W0t, E_, H_);
  gather_embed<<<4096, 256, 0, stream>>>(tokens, emb, Xg);
  make_frag_w<<<512, 256, 0, stream>>>(U0, U0f, H_);
  make_frag_w<<<512, 256, 0, stream>>>(W1, W1f, H_);
  make_frag_w<<<512, 256, 0, stream>>>(U1, U1f, H_);
  make_frag_w<<<16000, 256, 0, stream>>>(Wd, Wdf, V_);  // frag-linear Wd
  hipMemsetAsync(flags, 0, 4096, stream);

  // xw = Xg @ W0 + b0   (M=4096, N=1024, K=512)
  gemm_bf16_tn<<<dim3(H_ / 128, 4096 / 128), 256, 0, stream>>>(Xg, W0t, b0, xw, 4096, H_, E_);

  // fused: recurrence (48 WGs) + one-tile vocab GEMM WGs (4000, mt-major)
  rnn_vocab_fused<<<NWGS + GWGS, 512, 0, stream>>>(U0f, W1f, U1f, xw, b1, h0buf, h1buf, Yf,
                                                   flags, Wdf, bd, out);
}

// Round 18
// 1030.971 us; speedup vs baseline: 1.3513x; 1.0556x over previous
//
#include <hip/hip_runtime.h>
#include <hip/hip_bf16.h>
#include <cstdint>

typedef __attribute__((ext_vector_type(8))) short bf16x8;
typedef __attribute__((ext_vector_type(4))) float f32x4;
typedef __attribute__((ext_vector_type(4))) unsigned int u32x4;

#define V_ 32000
#define E_ 512
#define H_ 1024
#define B_ 32
#define S_ 128

#define L1WG 16   // 16 WGs x 64 cols (layer 1)
#define L2WG 32   // 32 WGs x 32 cols (layer 2)
#define NWGS 48
#define NTILES 250          // V_/128 n-bands
#define GWGS (16 * NTILES)  // one-tile GEMM WGs, mt-major dispatch

// ---- async global->LDS, 16B per lane (dest = wave-uniform base + lane*16) ----
typedef __attribute__((address_space(1))) unsigned int* gas1_t;
typedef __attribute__((address_space(3))) unsigned int* las3_t;
__device__ __forceinline__ void load_lds16(const void* g, void* l) {
  __builtin_amdgcn_global_load_lds((gas1_t)g, (las3_t)l, 16, 0, 0);
}

// ---- coherent exchange primitives (visibility proven R4..R17) ----
__device__ __forceinline__ void ldx4_sc(u32x4* d, const void* p) {
  asm volatile("global_load_dwordx4 %0, %1, off sc0 sc1" : "=v"(*d) : "v"(p) : "memory");
}
__device__ __forceinline__ unsigned ld_sc(const unsigned* p) {
  unsigned d;
  asm volatile("global_load_dword %0, %1, off sc0 sc1\n\ts_waitcnt vmcnt(0)"
               : "=v"(d) : "v"(p) : "memory");
  return d;
}
__device__ __forceinline__ void st_swap(unsigned* p, unsigned v) {
  asm volatile("global_atomic_swap %0, %1, off sc1" :: "v"(p), "v"(v) : "memory");
}
__device__ __forceinline__ void st_swap2(uint2* p, uint2 v) {
  asm volatile("global_atomic_swap_x2 %0, %1, off sc1" :: "v"(p), "v"(v) : "memory");
}
#define WAITVM0()                                     \
  asm volatile("s_waitcnt vmcnt(0)" ::: "memory");    \
  __builtin_amdgcn_sched_barrier(0)
#define WAITVM6()                                     \
  asm volatile("s_waitcnt vmcnt(6)" ::: "memory");    \
  __builtin_amdgcn_sched_barrier(0)

__device__ __forceinline__ unsigned short bfbits(float x) {
  __hip_bfloat16 b = __float2bfloat16(x);
  union { __hip_bfloat16 b; unsigned short u; } c;
  c.b = b;
  return c.u;
}

// pack 4 rows x 4 cols into one uint2 per lane (2 shfl_xor rounds) — proven R5+
__device__ __forceinline__ uint2 pack_rows(const float f[4], int lane, int j) {
  uint2 v2[4];
#pragma unroll
  for (int r = 0; r < 4; ++r) {
    const float o = __shfl_xor(f[r], 1);
    const float lo = (lane & 1) ? o : f[r];
    const float hi = (lane & 1) ? f[r] : o;
    const unsigned pk = (unsigned)bfbits(lo) | ((unsigned)bfbits(hi) << 16);
    const unsigned q2 = __shfl_xor(pk, 2);
    v2[r].x = (j & 2) ? q2 : pk;
    v2[r].y = (j & 2) ? pk : q2;
  }
  const int rs = lane & 3;
  return rs == 0 ? v2[0] : rs == 1 ? v2[1] : rs == 2 ? v2[2] : v2[3];
}

// ---- transpose + f32->bf16 : src[R][C] -> dst[C][R] (W0 only) ----
__global__ __launch_bounds__(256) void transpose_f32_bf16(
    const float* __restrict__ src, __hip_bfloat16* __restrict__ dst, int R, int C) {
  __shared__ float tile[32][33];
  const int c0 = blockIdx.x << 5, r0 = blockIdx.y << 5;
  const int tx = threadIdx.x & 31, ty = threadIdx.x >> 5;
#pragma unroll
  for (int i = 0; i < 32; i += 8)
    tile[ty + i][tx] = src[(size_t)(r0 + ty + i) * C + (c0 + tx)];
  __syncthreads();
#pragma unroll
  for (int i = 0; i < 32; i += 8)
    dst[(size_t)(c0 + ty + i) * R + (r0 + tx)] = __float2bfloat16(tile[tx][ty + i]);
}

// ---- embedding gather -> bf16, rows ordered r = t*32 + b ----
__global__ __launch_bounds__(256) void gather_embed(
    const int* __restrict__ tokens, const float* __restrict__ emb,
    __hip_bfloat16* __restrict__ Xg) {
  const int r = blockIdx.x;
  const int t = r >> 5, b = r & 31;
  const int tok = tokens[b * S_ + t];
  const float* e = emb + (size_t)tok * E_;
  __hip_bfloat16* o = Xg + (size_t)r * E_;
  for (int k = threadIdx.x; k < E_; k += 256) o[k] = __float2bfloat16(e[k]);
}

// ---- f32 weight [K][ncols] -> MFMA B-fragment-linear bf16 ----
__global__ __launch_bounds__(256) void make_frag_w(
    const float* __restrict__ W, __hip_bfloat16* __restrict__ F, int ncols) {
  const int idx = blockIdx.x * 256 + threadIdx.x;
  const int lane = idx & 63, kb = (idx >> 6) & 31, g = idx >> 11;
  const int j = (g << 4) + (lane & 15);
  const int kbase = (kb << 5) + ((lane >> 4) << 3);
  __hip_bfloat16* o = F + (size_t)idx * 8;
#pragma unroll
  for (int e = 0; e < 8; ++e) o[e] = __float2bfloat16(W[(size_t)(kbase + e) * ncols + j]);
}

// ---- standalone 128x128 GEMM (xw only): 2-phase dbuf + XCD swizzle ----
__global__ __launch_bounds__(256) void gemm_bf16_tn(
    const __hip_bfloat16* __restrict__ A, const __hip_bfloat16* __restrict__ Bt,
    const float* __restrict__ bias, float* __restrict__ C, int M, int N, int K) {
  __shared__ __hip_bfloat16 ldsA[2][128 * 64];
  __shared__ __hip_bfloat16 ldsB[2][128 * 64];
  const int nwg = gridDim.x * gridDim.y;
  int L = blockIdx.y * gridDim.x + blockIdx.x;
  L = ((L & 7) * (nwg >> 3)) + (L >> 3);
  const int m0 = (L / gridDim.x) << 7;
  const int n0 = (L % gridDim.x) << 7;
  const int tid = threadIdx.x, wave = tid >> 6, lane = tid & 63;
  const int wr = wave >> 1, wc = wave & 1;
  f32x4 acc[4][4];
#pragma unroll
  for (int i = 0; i < 4; ++i)
#pragma unroll
    for (int jj = 0; jj < 4; ++jj) acc[i][jj] = (f32x4){0.f, 0.f, 0.f, 0.f};

  auto stage = [&](int buf, int k0) {
#pragma unroll
    for (int i = 0; i < 4; ++i) {
      const int c = i * 4 + wave;
      const int idx = (c << 6) + lane;
      const int row = idx >> 3, kk = (idx & 7) << 3;
      load_lds16(A + (size_t)(m0 + row) * K + (k0 + kk), &ldsA[buf][c * 512]);
      load_lds16(Bt + (size_t)(n0 + row) * K + (k0 + kk), &ldsB[buf][c * 512]);
    }
  };
  stage(0, 0);
  __syncthreads();
  int cur = 0;
  for (int k0 = 0; k0 < K; k0 += 64) {
    if (k0 + 64 < K) stage(cur ^ 1, k0 + 64);
    __builtin_amdgcn_s_setprio(1);
#pragma unroll
    for (int ks = 0; ks < 2; ++ks) {
      bf16x8 af[4], bfr[4];
#pragma unroll
      for (int mi = 0; mi < 4; ++mi)
        af[mi] = *(const bf16x8*)(&ldsA[cur][0] +
                                  (((wr << 6) + (mi << 4) + (lane & 15)) << 6) +
                                  (ks << 5) + ((lane >> 4) << 3));
#pragma unroll
      for (int ni = 0; ni < 4; ++ni)
        bfr[ni] = *(const bf16x8*)(&ldsB[cur][0] +
                                   (((wc << 6) + (ni << 4) + (lane & 15)) << 6) +
                                   (ks << 5) + ((lane >> 4) << 3));
#pragma unroll
      for (int mi = 0; mi < 4; ++mi)
#pragma unroll
        for (int ni = 0; ni < 4; ++ni)
          acc[mi][ni] =
              __builtin_amdgcn_mfma_f32_16x16x32_bf16(af[mi], bfr[ni], acc[mi][ni], 0, 0, 0);
    }
    __builtin_amdgcn_s_setprio(0);
    __syncthreads();
    cur ^= 1;
  }
#pragma unroll
  for (int mi = 0; mi < 4; ++mi) {
#pragma unroll
    for (int ni = 0; ni < 4; ++ni) {
      const int n = n0 + (wc << 6) + (ni << 4) + (lane & 15);
      const float bn = bias[n];
#pragma unroll
      for (int r = 0; r < 4; ++r) {
        const int m = m0 + (wr << 6) + (mi << 4) + ((lane >> 4) << 2) + r;
        C[(size_t)m * N + n] = acc[mi][ni][r] + bn;
      }
    }
  }
}

// ============================================================================
// FUSED kernel (R17 structure). Single change vs R17: `out` epilogue uses
// NON-TEMPORAL stores so the 524MB output stream doesn't evict Wdf from L3
// (R17 counters: FETCH 677MB = Wdf re-fetched ~10x from HBM; the GEMM WGs
// were stalled on HBM-latency B-loads).
// ============================================================================
__global__ __launch_bounds__(512, 1) void rnn_vocab_fused(
    const __hip_bfloat16* __restrict__ U0f, const __hip_bfloat16* __restrict__ W1f,
    const __hip_bfloat16* __restrict__ U1f, const float* __restrict__ xw,
    const float* __restrict__ b1,
    __hip_bfloat16* __restrict__ h0buf,  // [4][32][1024] ring-4
    __hip_bfloat16* __restrict__ h1buf,  // [2][32][1024] ring-2
    __hip_bfloat16* __restrict__ Yf,     // frag-linear A: 8MB
    unsigned* __restrict__ flags,        // [48*16] dwords, zeroed
    const __hip_bfloat16* __restrict__ Wdf,  // frag-linear Wd: 64MB
    const float* __restrict__ bd, float* __restrict__ out) {
  __shared__ char smem[135168];
  const int tid = threadIdx.x, wave = tid >> 6, lane = tid & 63;

  if (blockIdx.x < NWGS) {
    // ======================= recurrence (R9 verbatim) =======================
    char* sA0 = smem;
    char* sA1 = smem + 65536;
    float* pad = (float*)(smem + 131072);
    const int g = blockIdx.x;
    const bool isL1 = (g < L1WG);
    const int mi = wave & 1;
    const int cg = isL1 ? (wave >> 1) : ((wave >> 1) & 1);
    const int mat = isL1 ? 0 : (wave >> 2);
    const int colbase = isL1 ? (g << 6) : ((g - L1WG) << 5);
    const int j = colbase + (cg << 4) + (lane & 15);
    const int gg = (colbase >> 4) + cg;
    const int rowbase = (mi << 4) + ((lane >> 4) << 2);
    const int rs = lane & 3;
    const int ra = (mi << 4) + (lane & 15);
    const int q4 = (lane >> 4) << 4;
    const float b1j = b1[j];

    const __hip_bfloat16* wb = isL1 ? U0f : (mat == 0 ? W1f : U1f);
    bf16x8 wfr[32];
#pragma unroll
    for (int kb = 0; kb < 32; ++kb)
      wfr[kb] = *(const bf16x8*)(wb + (size_t)((((gg << 5) + kb) << 6) + lane) * 8);

    if (!isL1) {
      for (int i = tid; i < 4096; i += 512) *(uint4*)(sA1 + i * 16) = (uint4){0u, 0u, 0u, 0u};
    }
    __syncthreads();

    const int stg_row = tid >> 7;
    const int stg_colb = (tid & 127) << 4;
    const unsigned* fpoll = flags + ((lane < NWGS ? lane : NWGS - 1) << 4);

    if (isL1) {
      for (int p = 0; p < S_; ++p) {
        const float* xrow = xw + ((size_t)p << 15);
        float xv[4];
#pragma unroll
        for (int r = 0; r < 4; ++r) xv[r] = xrow[(rowbase + r) * H_ + j];
        if (p >= 1) {
          const unsigned tgt =
              (lane < L1WG) ? (unsigned)p : (p >= 3 ? (unsigned)(p - 3) : 0u);
          unsigned v;
          do { v = ld_sc(fpoll); } while (__any(v < tgt));
          const char* src0 = (const char*)(h0buf + ((size_t)((p - 1) & 3) << 15));
          u32x4 t0[8];
#pragma unroll
          for (int i = 0; i < 8; ++i) ldx4_sc(&t0[i], src0 + (size_t)(((i << 9) + tid) << 4));
          WAITVM0();
#pragma unroll
          for (int i = 0; i < 8; ++i) {
            const int row = stg_row + (i << 2);
            *(u32x4*)(sA0 + (row << 11) + (stg_colb ^ ((row & 7) << 4))) = t0[i];
          }
          __syncthreads();
        }
        f32x4 acc = {0.f, 0.f, 0.f, 0.f};
        if (p >= 1) {
#pragma unroll
          for (int kb = 0; kb < 32; ++kb) {
            bf16x8 a = *(const bf16x8*)(
                sA0 + (ra << 11) + ((((kb << 6) + q4)) ^ ((ra & 7) << 4)));
            acc = __builtin_amdgcn_mfma_f32_16x16x32_bf16(a, wfr[kb], acc, 0, 0, 0);
          }
        }
        float f[4];
#pragma unroll
        for (int r = 0; r < 4; ++r) f[r] = tanhf(acc[r] + xv[r]);
        uint2 vsel = pack_rows(f, lane, j);
        uint2* h4 = (uint2*)(h0buf + ((size_t)(p & 3) << 15));
        st_swap2(h4 + (rowbase + rs) * (H_ / 4) + (j >> 2), vsel);
        WAITVM0();
        __syncthreads();
        if (tid == 0) st_swap(flags + (g << 4), (unsigned)(p + 1));
      }
    } else {
      for (int t = 0; t < S_; ++t) {
        {
          const unsigned tgt = (lane < L1WG) ? (unsigned)(t + 1) : (unsigned)t;
          unsigned v;
          do { v = ld_sc(fpoll); } while (__any(v < tgt));
        }
        {
          const char* src0 = (const char*)(h0buf + ((size_t)(t & 3) << 15));
          u32x4 t0[8], t1[8];
#pragma unroll
          for (int i = 0; i < 8; ++i) ldx4_sc(&t0[i], src0 + (size_t)(((i << 9) + tid) << 4));
          if (t >= 1) {
            const char* src1 = (const char*)(h1buf + ((size_t)((t - 1) & 1) << 15));
#pragma unroll
            for (int i = 0; i < 8; ++i) ldx4_sc(&t1[i], src1 + (size_t)(((i << 9) + tid) << 4));
          }
          WAITVM0();
#pragma unroll
          for (int i = 0; i < 8; ++i) {
            const int row = stg_row + (i << 2);
            *(u32x4*)(sA0 + (row << 11) + (stg_colb ^ ((row & 7) << 4))) = t0[i];
          }
          if (t >= 1) {
#pragma unroll
            for (int i = 0; i < 8; ++i) {
              const int row = stg_row + (i << 2);
              *(u32x4*)(sA1 + (row << 11) + (stg_colb ^ ((row & 7) << 4))) = t1[i];
            }
          }
          __syncthreads();
        }
        const char* sA = (mat == 0) ? sA0 : sA1;
        f32x4 acc = {0.f, 0.f, 0.f, 0.f};
#pragma unroll
        for (int kb = 0; kb < 32; ++kb) {
          bf16x8 a = *(const bf16x8*)(
              sA + (ra << 11) + ((((kb << 6) + q4)) ^ ((ra & 7) << 4)));
          acc = __builtin_amdgcn_mfma_f32_16x16x32_bf16(a, wfr[kb], acc, 0, 0, 0);
        }
        const int pair = wave & 3;
        if (mat == 0) *(f32x4*)(pad + pair * 256 + lane * 4) = acc;
        __syncthreads();
        if (mat == 1) {
          f32x4 accW = *(const f32x4*)(pad + pair * 256 + lane * 4);
          float f[4];
#pragma unroll
          for (int r = 0; r < 4; ++r) f[r] = tanhf(acc[r] + accW[r] + b1j);
          uint2 vsel = pack_rows(f, lane, j);
          const int bb = rowbase + rs;
          uint2* h4 = (uint2*)(h1buf + ((size_t)(t & 1) << 15));
          st_swap2(h4 + bb * (H_ / 4) + (j >> 2), vsel);
          const int jb = j & ~3;
          const size_t fo =
              (((size_t)((t << 1) + (bb >> 4)) << 5) + (jb >> 5)) * 64 +
              (((jb >> 3) & 3) << 4) + (bb & 15);
          st_swap2((uint2*)((char*)Yf + fo * 16 + ((jb & 7) << 1)), vsel);
        }
        WAITVM0();
        __syncthreads();
        if (tid == 0) st_swap(flags + (g << 4), (unsigned)(t + 1));
      }
    }
    return;
  }

  // =================== one-tile vocab GEMM WGs (mt-major) ===================
  const int bid = blockIdx.x - NWGS;
  const int mt = bid / NTILES, nt = bid - mt * NTILES;
  const int m0 = mt << 8, n0 = nt << 7;
  {
    const unsigned tgt = (unsigned)((mt << 3) + 8);
    if (wave == 0) {
      const unsigned* fp = flags + ((L1WG + (lane & 31)) << 4);
      while (true) {
        unsigned v = ld_sc(fp);
        if (!__any(v < tgt)) break;
        asm volatile("s_sleep 4");
      }
    }
    __syncthreads();
  }
  const int wr = wave >> 1, wc = wave & 1;  // 4M x 2N waves, 64x64 each
  const char* Yc = (const char*)Yf;
  const char* Wc = (const char*)Wdf;
  f32x4 acc[4][4];
#pragma unroll
  for (int i = 0; i < 4; ++i)
#pragma unroll
    for (int jj = 0; jj < 4; ++jj) acc[i][jj] = (f32x4){0.f, 0.f, 0.f, 0.f};

  auto stageA = [&](int buf, int k0) {  // 32 chunks, 4/wave
#pragma unroll
    for (int i = 0; i < 4; ++i) {
      const int c = (i << 3) + wave;
      const char* src = Yc +
          ((((size_t)(m0 >> 4) + (c >> 1)) << 5) + (k0 >> 5) + (c & 1)) * 1024 +
          (lane << 4);
      load_lds16(src, smem + buf * 32768 + c * 1024);
    }
  };
  auto stageB = [&](int buf, int k0) {  // 16 chunks, 2/wave
#pragma unroll
    for (int i = 0; i < 2; ++i) {
      const int c = (i << 3) + wave;
      const char* src = Wc +
          ((((size_t)(n0 >> 4) + (c >> 1)) << 5) + (k0 >> 5) + (c & 1)) * 1024 +
          (lane << 4);
      load_lds16(src, smem + 65536 + buf * 16384 + c * 1024);
    }
  };

  stageA(0, 0);
  stageB(0, 0);
  stageA(1, 64);
  stageB(1, 64);
  WAITVM6();  // tile0's 6/wave done; tile1's 6 in flight
  __builtin_amdgcn_sched_barrier(0);
  __builtin_amdgcn_s_barrier();
  int cur = 0;
  for (int k0 = 0; k0 < H_; k0 += 64) {
    __builtin_amdgcn_s_setprio(1);
#pragma unroll
    for (int ks = 0; ks < 2; ++ks) {
      bf16x8 af[4], bfr[4];
#pragma unroll
      for (int mi = 0; mi < 4; ++mi)
        af[mi] = *(const bf16x8*)(smem + cur * 32768 +
                                  ((((wr << 2) + mi) << 1) + ks) * 1024 + (lane << 4));
#pragma unroll
      for (int ni = 0; ni < 4; ++ni)
        bfr[ni] = *(const bf16x8*)(smem + 65536 + cur * 16384 +
                                   ((((wc << 2) + ni) << 1) + ks) * 1024 + (lane << 4));
#pragma unroll
      for (int mi = 0; mi < 4; ++mi)
#pragma unroll
        for (int ni = 0; ni < 4; ++ni)
          acc[mi][ni] = __builtin_amdgcn_mfma_f32_16x16x32_bf16(af[mi], bfr[ni],
                                                                acc[mi][ni], 0, 0, 0);
    }
    __builtin_amdgcn_s_setprio(0);
    if (k0 + 64 < H_) {
      __builtin_amdgcn_sched_barrier(0);
      __builtin_amdgcn_s_barrier();  // all waves done reading buf[cur]
      if (k0 + 128 < H_) {
        stageA(cur, k0 + 128);       // refill freed buffer
        stageB(cur, k0 + 128);
        WAITVM6();                   // prev tile's 6 done; new 6 in flight
      } else {
        WAITVM0();                   // last prefetch already issued: drain
      }
      __builtin_amdgcn_sched_barrier(0);
      __builtin_amdgcn_s_barrier();  // buf[cur^1] certified staged
      cur ^= 1;
    }
  }
  // epilogue: m = t*32+b -> out row = b*128+t ; add bd ; NON-TEMPORAL stores
#pragma unroll
  for (int mi = 0; mi < 4; ++mi) {
#pragma unroll
    for (int ni = 0; ni < 4; ++ni) {
      const int n = n0 + (wc << 6) + (ni << 4) + (lane & 15);
      const float bn = bd[n];
#pragma unroll
      for (int r = 0; r < 4; ++r) {
        const int m = m0 + (wr << 6) + (mi << 4) + ((lane >> 4) << 2) + r;
        const size_t orow = (size_t)(m & 31) * S_ + (m >> 5);
        __builtin_nontemporal_store(acc[mi][ni][r] + bn, &out[orow * V_ + n]);
      }
    }
  }
}

extern "C" void kernel_launch(void* const* d_in, const int* in_sizes, int n_in, void* d_out,
                              int out_size, void* d_ws, size_t ws_size, hipStream_t stream) {
  const int* tokens = (const int*)d_in[0];
  const float* emb = (const float*)d_in[1];
  const float* W0 = (const float*)d_in[2];
  const float* U0 = (const float*)d_in[3];
  const float* b0 = (const float*)d_in[4];
  const float* W1 = (const float*)d_in[5];
  const float* U1 = (const float*)d_in[6];
  const float* b1 = (const float*)d_in[7];
  const float* Wd = (const float*)d_in[8];
  const float* bd = (const float*)d_in[9];
  float* out = (float*)d_out;

  char* ws = (char*)d_ws;
  __hip_bfloat16* Wdf = (__hip_bfloat16*)ws;  ws += (size_t)V_ * H_ * 2;       // 64MB frag-linear
  __hip_bfloat16* W0t = (__hip_bfloat16*)ws;  ws += (size_t)H_ * E_ * 2;       // 1MB
  __hip_bfloat16* Xg = (__hip_bfloat16*)ws;   ws += (size_t)4096 * E_ * 2;     // 4MB
  __hip_bfloat16* U0f = (__hip_bfloat16*)ws;  ws += (size_t)H_ * H_ * 2;       // 2MB
  __hip_bfloat16* W1f = (__hip_bfloat16*)ws;  ws += (size_t)H_ * H_ * 2;       // 2MB
  __hip_bfloat16* U1f = (__hip_bfloat16*)ws;  ws += (size_t)H_ * H_ * 2;       // 2MB
  float* xw = (float*)ws;                     ws += (size_t)4096 * H_ * 4;     // 16MB
  __hip_bfloat16* h0buf = (__hip_bfloat16*)ws; ws += 4 * B_ * H_ * 2;          // 256KB
  __hip_bfloat16* h1buf = (__hip_bfloat16*)ws; ws += 2 * B_ * H_ * 2;          // 128KB
  __hip_bfloat16* Yf = (__hip_bfloat16*)ws;   ws += (size_t)4096 * H_ * 2;     // 8MB frag-linear
  unsigned* flags = (unsigned*)ws;            ws += 4096;

  // prep
  transpose_f32_bf16<<<dim3(H_ / 32, E_ / 32), 256, 0, stream>>>(W0, W0t, E_, H_);
  gather_embed<<<4096, 256, 0, stream>>>(tokens, emb, Xg);
  make_frag_w<<<512, 256, 0, stream>>>(U0, U0f, H_);
  make_frag_w<<<512, 256, 0, stream>>>(W1, W1f, H_);
  make_frag_w<<<512, 256, 0, stream>>>(U1, U1f, H_);
  make_frag_w<<<16000, 256, 0, stream>>>(Wd, Wdf, V_);  // frag-linear Wd
  hipMemsetAsync(flags, 0, 4096, stream);

  // xw = Xg @ W0 + b0   (M=4096, N=1024, K=512)
  gemm_bf16_tn<<<dim3(H_ / 128, 4096 / 128), 256, 0, stream>>>(Xg, W0t, b0, xw, 4096, H_, E_);

  // fused: recurrence (48 WGs) + one-tile vocab GEMM WGs (4000, mt-major)
  rnn_vocab_fused<<<NWGS + GWGS, 512, 0, stream>>>(U0f, W1f, U1f, xw, b1, h0buf, h1buf, Yf,
                                                   flags, Wdf, bd, out);
}